// Round 1
// baseline (842.356 us; speedup 1.0000x reference)
//
#include <hip/hip_runtime.h>
#include <math.h>

#define NB 16
#define NL 64
#define NK 32
#define NC 32
#define ND 512
#define SEP_THRESHOLD 5.0f
#define EPSF 1e-10f

// ws layout (floats): [0..3] accumulators {attN, attD, repN, repD},
// P at float offset 1024, LP at float offset 1024 + NB*NL*NK*NC.

__global__ void init_acc_kernel(float* acc) {
    if (threadIdx.x < 4) acc[threadIdx.x] = 0.0f;
}

// One 32-lane group per (b,l,k) row of C=32. 8 rows per 256-thread block.
__global__ void softmax_kernel(const float* __restrict__ prior,
                               float* __restrict__ P,
                               float* __restrict__ LP) {
    int tid = threadIdx.x;
    int row = blockIdx.x * 8 + (tid >> 5);
    int c = tid & 31;
    float x = prior[(size_t)row * NC + c];
    float m = x;
    #pragma unroll
    for (int w = 16; w >= 1; w >>= 1)
        m = fmaxf(m, __shfl_xor(m, w, 32));
    float e = expf(x - m);
    float s = e;
    #pragma unroll
    for (int w = 16; w >= 1; w >>= 1)
        s += __shfl_xor(s, w, 32);
    float lse = logf(s);
    float lp = (x - m) - lse;
    size_t idx = (size_t)row * NC + c;
    P[idx]  = e / s;
    LP[idx] = lp;
}

// One wave (64 lanes) per (b, i, j) pair, j > i.
__global__ void pair_kernel(const float* __restrict__ P,
                            const float* __restrict__ LP,
                            const float* __restrict__ h,
                            float* __restrict__ acc) {
    int bi = blockIdx.x;            // b*NL + i
    int j  = blockIdx.y;
    int i  = bi & (NL - 1);
    int b  = bi >> 6;
    if (j <= i) return;
    int lane = threadIdx.x;

    const float* p1  = P  + (size_t)bi * (NK * NC);
    const float* lp1 = LP + (size_t)bi * (NK * NC);
    const float* p2  = P  + (size_t)(b * NL + j) * (NK * NC);
    const float* lp2 = LP + (size_t)(b * NL + j) * (NK * NC);

    float jacc = 0.0f;
    #pragma unroll
    for (int s = 0; s < (NK * NC) / 64; ++s) {
        int e = lane + 64 * s;
        float a  = p1[e],  la = lp1[e];
        float bb = p2[e],  lb = lp2[e];
        float logm = logf(0.5f * (a + bb));
        jacc += a * (la - logm) + bb * (lb - logm);
    }

    const float* hi = h + (size_t)bi * ND;
    const float* hj = h + (size_t)(b * NL + j) * ND;
    float macc = 0.0f;
    #pragma unroll
    for (int s = 0; s < ND / 64; ++s) {
        float d = hi[lane + 64 * s] - hj[lane + 64 * s];
        macc = fmaf(d, d, macc);
    }

    #pragma unroll
    for (int w = 32; w >= 1; w >>= 1) {
        jacc += __shfl_xor(jacc, w);
        macc += __shfl_xor(macc, w);
    }

    if (lane == 0) {
        float jsd = 0.5f * jacc;          // SCALING_FACTOR = 1
        float mse = macc * (1.0f / ND);
        if (jsd < SEP_THRESHOLD) {
            atomicAdd(&acc[0], mse);
            atomicAdd(&acc[1], 1.0f);
        } else {
            atomicAdd(&acc[2], expf(-mse)); // DIST_TEMPERATURE = 1
            atomicAdd(&acc[3], 1.0f);
        }
    }
}

__global__ void finalize_kernel(const float* __restrict__ acc,
                                float* __restrict__ out) {
    float la = acc[0] / (acc[1] + EPSF);
    float lr = acc[2] / (acc[3] + EPSF);
    out[0] = (la > 0.0f) ? la : 0.0f;   // ATT_LOSS_GATE = 0
    out[1] = (lr > 0.0f) ? lr : 0.0f;   // REP_LOSS_GATE = 0
}

extern "C" void kernel_launch(void* const* d_in, const int* in_sizes, int n_in,
                              void* d_out, int out_size, void* d_ws, size_t ws_size,
                              hipStream_t stream) {
    const float* prior = (const float*)d_in[0];
    const float* h     = (const float*)d_in[1];
    float* out = (float*)d_out;
    float* ws  = (float*)d_ws;

    float* acc = ws;                       // 4 floats
    float* P   = ws + 1024;                // NB*NL*NK*NC floats
    float* LP  = P + (size_t)NB * NL * NK * NC;

    init_acc_kernel<<<1, 64, 0, stream>>>(acc);

    // 32768 rows, 8 rows per block
    softmax_kernel<<<(NB * NL * NK) / 8, 256, 0, stream>>>(prior, P, LP);

    dim3 grid(NB * NL, NL);
    pair_kernel<<<grid, 64, 0, stream>>>(P, LP, h, acc);

    finalize_kernel<<<1, 1, 0, stream>>>(acc, out);
}

// Round 2
// 50.984 us; speedup vs baseline: 16.5221x; 16.5221x over previous
//
#include <hip/hip_runtime.h>
#include <math.h>

#define NB 16
#define NL 64
#define NK 32
#define NC 32
#define ND 512
#define SEP_THRESHOLD 5.0f
#define EPSF 1e-10f

#define NPAIR_B 2016                  // L*(L-1)/2
#define NPAIR   (NB * NPAIR_B)        // 32256
#define PAIR_BLOCKS 1008              // 4 waves each -> 4032 waves -> exactly 8 pairs/wave
#define PAIRS_PER_WAVE 8

// ws layout (floats):
//   partials: PAIR_BLOCKS*4 floats at offset 0  {attN, attCnt, repN, repCnt} per block
//   P  at float offset 8192
//   LP at P + NB*NL*NK*NC

// One 32-lane group per (b,l,k) row of C=32. 8 rows per 256-thread block.
__global__ void softmax_kernel(const float* __restrict__ prior,
                               float* __restrict__ P,
                               float* __restrict__ LP) {
    int tid = threadIdx.x;
    int row = blockIdx.x * 8 + (tid >> 5);
    int c = tid & 31;
    float x = prior[(size_t)row * NC + c];
    float m = x;
    #pragma unroll
    for (int w = 16; w >= 1; w >>= 1)
        m = fmaxf(m, __shfl_xor(m, w, 32));
    float e = expf(x - m);
    float s = e;
    #pragma unroll
    for (int w = 16; w >= 1; w >>= 1)
        s += __shfl_xor(s, w, 32);
    float lse = logf(s);
    size_t idx = (size_t)row * NC + c;
    P[idx]  = e / s;
    LP[idx] = (x - m) - lse;
}

__device__ __forceinline__ int tri_off(int i) {
    return (i * (2 * NL - 1 - i)) >> 1;   // i*(127-i)/2
}

// 4 waves/block, each wave handles PAIRS_PER_WAVE pairs; block writes 4 partials.
__global__ void __launch_bounds__(256) pair_kernel(
        const float* __restrict__ P,
        const float* __restrict__ LP,
        const float* __restrict__ h,
        float* __restrict__ partials) {
    int tid  = threadIdx.x;
    int lane = tid & 63;
    int wib  = tid >> 6;                       // wave in block
    int wave = blockIdx.x * 4 + wib;           // 0..4031

    float attN = 0.0f, attC = 0.0f, repN = 0.0f, repC = 0.0f;

    #pragma unroll
    for (int s = 0; s < PAIRS_PER_WAVE; ++s) {
        int pid = wave + s * (PAIR_BLOCKS * 4);    // < NPAIR
        int b = pid / NPAIR_B;
        int r = pid - b * NPAIR_B;

        // decode i from triangular offset, then fix up
        float t = sqrtf((float)(16129 - 8 * r));   // (2L-1)^2 - 8r
        int i = (int)((127.0f - t) * 0.5f);
        if (i > 0 && r < tri_off(i)) --i;
        if (r >= tri_off(i + 1)) ++i;
        int j = r - tri_off(i) + i + 1;

        const float* p1  = P  + ((size_t)(b * NL + i)) * (NK * NC);
        const float* lp1 = LP + ((size_t)(b * NL + i)) * (NK * NC);
        const float* p2  = P  + ((size_t)(b * NL + j)) * (NK * NC);
        const float* lp2 = LP + ((size_t)(b * NL + j)) * (NK * NC);

        float jacc = 0.0f;
        #pragma unroll
        for (int e = 0; e < (NK * NC) / 64; ++e) {
            int idx = lane + 64 * e;
            float a  = p1[idx],  la = lp1[idx];
            float bb = p2[idx],  lb = lp2[idx];
            float logm = logf(0.5f * (a + bb));
            jacc += a * la + bb * lb - (a + bb) * logm;
        }

        const float* hi = h + ((size_t)(b * NL + i)) * ND;
        const float* hj = h + ((size_t)(b * NL + j)) * ND;
        float macc = 0.0f;
        #pragma unroll
        for (int e = 0; e < ND / 64; ++e) {
            float d = hi[lane + 64 * e] - hj[lane + 64 * e];
            macc = fmaf(d, d, macc);
        }

        #pragma unroll
        for (int w = 32; w >= 1; w >>= 1) {
            jacc += __shfl_xor(jacc, w);
            macc += __shfl_xor(macc, w);
        }

        float jsd = 0.5f * jacc;                 // SCALING_FACTOR = 1
        float mse = macc * (1.0f / ND);
        if (jsd < SEP_THRESHOLD) { attN += mse;        attC += 1.0f; }
        else                     { repN += expf(-mse); repC += 1.0f; }
    }

    // all lanes hold identical wave accumulators; lane 0 publishes
    __shared__ float red[4][4];
    if (lane == 0) {
        red[wib][0] = attN; red[wib][1] = attC;
        red[wib][2] = repN; red[wib][3] = repC;
    }
    __syncthreads();
    if (tid < 4) {
        float v = red[0][tid] + red[1][tid] + red[2][tid] + red[3][tid];
        partials[blockIdx.x * 4 + tid] = v;
    }
}

__global__ void __launch_bounds__(256) finalize_kernel(
        const float* __restrict__ partials,
        float* __restrict__ out) {
    int tid = threadIdx.x;
    float a0 = 0.0f, a1 = 0.0f, a2 = 0.0f, a3 = 0.0f;
    for (int bkt = tid; bkt < PAIR_BLOCKS; bkt += 256) {
        a0 += partials[bkt * 4 + 0];
        a1 += partials[bkt * 4 + 1];
        a2 += partials[bkt * 4 + 2];
        a3 += partials[bkt * 4 + 3];
    }
    #pragma unroll
    for (int w = 32; w >= 1; w >>= 1) {
        a0 += __shfl_xor(a0, w);
        a1 += __shfl_xor(a1, w);
        a2 += __shfl_xor(a2, w);
        a3 += __shfl_xor(a3, w);
    }
    __shared__ float red[4][4];
    int lane = tid & 63, wib = tid >> 6;
    if (lane == 0) {
        red[wib][0] = a0; red[wib][1] = a1; red[wib][2] = a2; red[wib][3] = a3;
    }
    __syncthreads();
    if (tid == 0) {
        float s0 = red[0][0] + red[1][0] + red[2][0] + red[3][0];
        float s1 = red[0][1] + red[1][1] + red[2][1] + red[3][1];
        float s2 = red[0][2] + red[1][2] + red[2][2] + red[3][2];
        float s3 = red[0][3] + red[1][3] + red[2][3] + red[3][3];
        float la = s0 / (s1 + EPSF);
        float lr = s2 / (s3 + EPSF);
        out[0] = (la > 0.0f) ? la : 0.0f;   // ATT_LOSS_GATE = 0
        out[1] = (lr > 0.0f) ? lr : 0.0f;   // REP_LOSS_GATE = 0
    }
}

extern "C" void kernel_launch(void* const* d_in, const int* in_sizes, int n_in,
                              void* d_out, int out_size, void* d_ws, size_t ws_size,
                              hipStream_t stream) {
    const float* prior = (const float*)d_in[0];
    const float* h     = (const float*)d_in[1];
    float* out = (float*)d_out;
    float* ws  = (float*)d_ws;

    float* partials = ws;                      // PAIR_BLOCKS*4 floats
    float* P  = ws + 8192;
    float* LP = P + (size_t)NB * NL * NK * NC;

    softmax_kernel<<<(NB * NL * NK) / 8, 256, 0, stream>>>(prior, P, LP);

    pair_kernel<<<PAIR_BLOCKS, 256, 0, stream>>>(P, LP, h, partials);

    finalize_kernel<<<1, 256, 0, stream>>>(partials, out);
}

// Round 3
// 38.976 us; speedup vs baseline: 21.6124x; 1.3081x over previous
//
#include <hip/hip_runtime.h>
#include <math.h>

#define NB 16
#define NL 64
#define NK 32
#define NC 32
#define ND 512
#define EPSF 1e-10f

#define NPAIR_B 2016                  // L*(L-1)/2
#define NPAIR   (NB * NPAIR_B)        // 32256
#define PAIR_BLOCKS 1008              // 4 waves each -> 4032 waves -> exactly 8 pairs/wave
#define PAIRS_PER_WAVE 8

// att iff jsd < 5  <=>  (H2_i + H2_j - S + 64) < 10/ln2
#define STAT_THRESHOLD 14.426950408889634f
#define L2E 1.4426950408889634f

// ws layout (floats):
//   partials: PAIR_BLOCKS*4 floats at offset 0
//   P  at float offset 8192            (NB*NL*NK*NC floats = 4 MB)
//   H2 at P + NB*NL*NK*NC              (NB*NL floats)

// One block per (b,l): 256 threads x float4 = 1024 elements (32 k-rows of 32).
// Each 8-lane group owns one k-row. Computes P (softmax) and the row scalar
// H2[b,l] = sum_{k,c} p * log2(p).
__global__ void __launch_bounds__(256) softmax_kernel(
        const float* __restrict__ prior,
        float* __restrict__ P,
        float* __restrict__ H2) {
    int bl = blockIdx.x;
    int t  = threadIdx.x;
    const float* src = prior + (size_t)bl * (NK * NC);
    float*       dst = P     + (size_t)bl * (NK * NC);

    float4 x = *(const float4*)(src + t * 4);
    float y0 = x.x * L2E, y1 = x.y * L2E, y2 = x.z * L2E, y3 = x.w * L2E;

    float m = fmaxf(fmaxf(y0, y1), fmaxf(y2, y3));
    #pragma unroll
    for (int w = 4; w >= 1; w >>= 1)
        m = fmaxf(m, __shfl_xor(m, w, 8));      // 8 lanes per k-row

    float e0 = exp2f(y0 - m), e1 = exp2f(y1 - m);
    float e2 = exp2f(y2 - m), e3 = exp2f(y3 - m);
    float s = e0 + e1 + e2 + e3;
    #pragma unroll
    for (int w = 4; w >= 1; w >>= 1)
        s += __shfl_xor(s, w, 8);

    float rs = 1.0f / s;
    float ls = log2f(s);
    float p0 = e0 * rs, p1 = e1 * rs, p2 = e2 * rs, p3 = e3 * rs;
    float l0 = (y0 - m) - ls, l1 = (y1 - m) - ls;
    float l2 = (y2 - m) - ls, l3 = (y3 - m) - ls;

    float4 pv = make_float4(p0, p1, p2, p3);
    *(float4*)(dst + t * 4) = pv;

    float hacc = p0 * l0 + p1 * l1 + p2 * l2 + p3 * l3;
    // block reduce hacc -> H2[bl]
    #pragma unroll
    for (int w = 32; w >= 1; w >>= 1)
        hacc += __shfl_xor(hacc, w);
    __shared__ float red[4];
    int lane = t & 63, wib = t >> 6;
    if (lane == 0) red[wib] = hacc;
    __syncthreads();
    if (t == 0) H2[bl] = red[0] + red[1] + red[2] + red[3];
}

__device__ __forceinline__ int tri_off(int i) {
    return (i * (2 * NL - 1 - i)) >> 1;   // i*(127-i)/2
}

// 4 waves/block, each wave handles 8 CONSECUTIVE pairs (shares i-row in L1).
__global__ void __launch_bounds__(256) pair_kernel(
        const float* __restrict__ P,
        const float* __restrict__ H2,
        const float* __restrict__ h,
        float* __restrict__ partials) {
    int tid  = threadIdx.x;
    int lane = tid & 63;
    int wib  = tid >> 6;
    int wave = blockIdx.x * 4 + wib;           // 0..4031

    float attN = 0.0f, attC = 0.0f, repN = 0.0f, repC = 0.0f;

    #pragma unroll
    for (int s = 0; s < PAIRS_PER_WAVE; ++s) {
        int pid = wave * PAIRS_PER_WAVE + s;   // consecutive -> i-row reuse
        int b = pid / NPAIR_B;
        int r = pid - b * NPAIR_B;

        float tt = sqrtf((float)(16129 - 8 * r));   // (2L-1)^2 - 8r
        int i = (int)((127.0f - tt) * 0.5f);
        if (i > 0 && r < tri_off(i)) --i;
        if (r >= tri_off(i + 1)) ++i;
        int j = r - tri_off(i) + i + 1;

        int bi = b * NL + i, bj = b * NL + j;

        const float4* p1 = (const float4*)(P + (size_t)bi * (NK * NC));
        const float4* p2 = (const float4*)(P + (size_t)bj * (NK * NC));

        float S = 0.0f;
        #pragma unroll
        for (int e = 0; e < (NK * NC) / 256; ++e) {   // 4 batches of float4
            float4 a  = p1[lane + 64 * e];
            float4 bb = p2[lane + 64 * e];
            float t0 = a.x + bb.x, t1 = a.y + bb.y;
            float t2 = a.z + bb.z, t3 = a.w + bb.w;
            S = fmaf(t0, log2f(t0), S);
            S = fmaf(t1, log2f(t1), S);
            S = fmaf(t2, log2f(t2), S);
            S = fmaf(t3, log2f(t3), S);
        }

        const float4* hi = (const float4*)(h + (size_t)bi * ND);
        const float4* hj = (const float4*)(h + (size_t)bj * ND);
        float macc = 0.0f;
        #pragma unroll
        for (int e = 0; e < ND / 256; ++e) {          // 2 batches of float4
            float4 da = hi[lane + 64 * e];
            float4 db = hj[lane + 64 * e];
            float d0 = da.x - db.x, d1 = da.y - db.y;
            float d2 = da.z - db.z, d3 = da.w - db.w;
            macc = fmaf(d0, d0, macc);
            macc = fmaf(d1, d1, macc);
            macc = fmaf(d2, d2, macc);
            macc = fmaf(d3, d3, macc);
        }

        #pragma unroll
        for (int w = 32; w >= 1; w >>= 1) {
            S    += __shfl_xor(S, w);
            macc += __shfl_xor(macc, w);
        }

        float stat = H2[bi] + H2[bj] + 64.0f - S;
        float mse  = macc * (1.0f / ND);
        if (stat < STAT_THRESHOLD) { attN += mse; attC += 1.0f; }
        else { repN += exp2f(-mse * L2E); repC += 1.0f; }
    }

    __shared__ float red[4][4];
    if (lane == 0) {
        red[wib][0] = attN; red[wib][1] = attC;
        red[wib][2] = repN; red[wib][3] = repC;
    }
    __syncthreads();
    if (tid < 4) {
        float v = red[0][tid] + red[1][tid] + red[2][tid] + red[3][tid];
        partials[blockIdx.x * 4 + tid] = v;
    }
}

__global__ void __launch_bounds__(256) finalize_kernel(
        const float* __restrict__ partials,
        float* __restrict__ out) {
    int tid = threadIdx.x;
    float a0 = 0.0f, a1 = 0.0f, a2 = 0.0f, a3 = 0.0f;
    for (int bkt = tid; bkt < PAIR_BLOCKS; bkt += 256) {
        a0 += partials[bkt * 4 + 0];
        a1 += partials[bkt * 4 + 1];
        a2 += partials[bkt * 4 + 2];
        a3 += partials[bkt * 4 + 3];
    }
    #pragma unroll
    for (int w = 32; w >= 1; w >>= 1) {
        a0 += __shfl_xor(a0, w);
        a1 += __shfl_xor(a1, w);
        a2 += __shfl_xor(a2, w);
        a3 += __shfl_xor(a3, w);
    }
    __shared__ float red[4][4];
    int lane = tid & 63, wib = tid >> 6;
    if (lane == 0) {
        red[wib][0] = a0; red[wib][1] = a1; red[wib][2] = a2; red[wib][3] = a3;
    }
    __syncthreads();
    if (tid == 0) {
        float s0 = red[0][0] + red[1][0] + red[2][0] + red[3][0];
        float s1 = red[0][1] + red[1][1] + red[2][1] + red[3][1];
        float s2 = red[0][2] + red[1][2] + red[2][2] + red[3][2];
        float s3 = red[0][3] + red[1][3] + red[2][3] + red[3][3];
        float la = s0 / (s1 + EPSF);
        float lr = s2 / (s3 + EPSF);
        out[0] = (la > 0.0f) ? la : 0.0f;
        out[1] = (lr > 0.0f) ? lr : 0.0f;
    }
}

extern "C" void kernel_launch(void* const* d_in, const int* in_sizes, int n_in,
                              void* d_out, int out_size, void* d_ws, size_t ws_size,
                              hipStream_t stream) {
    const float* prior = (const float*)d_in[0];
    const float* h     = (const float*)d_in[1];
    float* out = (float*)d_out;
    float* ws  = (float*)d_ws;

    float* partials = ws;                      // PAIR_BLOCKS*4 floats
    float* P  = ws + 8192;
    float* H2 = P + (size_t)NB * NL * NK * NC;

    softmax_kernel<<<NB * NL, 256, 0, stream>>>(prior, P, H2);

    pair_kernel<<<PAIR_BLOCKS, 256, 0, stream>>>(P, H2, h, partials);

    finalize_kernel<<<1, 256, 0, stream>>>(partials, out);
}

// Round 4
// 34.061 us; speedup vs baseline: 24.7307x; 1.1443x over previous
//
#include <hip/hip_runtime.h>
#include <math.h>

#define NB 16
#define NL 64
#define NK 32
#define NC 32
#define ND 512
#define EPSF 1e-10f

// 8x8 row tiles over the upper triangle (with diagonal): 36 tiles/batch
#define TILES_PER_B 36
#define PAIR_BLOCKS (NB * TILES_PER_B)    // 576

// att iff jsd < 5  <=>  (H2_i + H2_j - S + 64) < 10/ln2
#define STAT_THRESHOLD 14.426950408889634f
#define L2E 1.4426950408889634f

typedef _Float16 half4v __attribute__((ext_vector_type(4)));
typedef _Float16 half8v __attribute__((ext_vector_type(8)));

// ws layout (floats):
//   partials: PAIR_BLOCKS*4 floats at offset 0 (pad to 4096)
//   P  (f16): 1,048,576 halves = 2 MB at float offset 4096
//   H2 (f32): NB*NL floats after P

// One block per (b,l): 256 threads, each 4 elems. 8-lane groups own one k-row.
// Writes P as f16 (clamped away from 0) and H2[b,l] = sum p*log2(p).
__global__ void __launch_bounds__(256) softmax_kernel(
        const float* __restrict__ prior,
        _Float16* __restrict__ P,
        float* __restrict__ H2) {
    int bl = blockIdx.x;
    int t  = threadIdx.x;
    const float* src = prior + (size_t)bl * (NK * NC);

    float4 x = *(const float4*)(src + t * 4);
    float y0 = x.x * L2E, y1 = x.y * L2E, y2 = x.z * L2E, y3 = x.w * L2E;

    float m = fmaxf(fmaxf(y0, y1), fmaxf(y2, y3));
    #pragma unroll
    for (int w = 4; w >= 1; w >>= 1)
        m = fmaxf(m, __shfl_xor(m, w, 8));      // 8 lanes per k-row

    float e0 = exp2f(y0 - m), e1 = exp2f(y1 - m);
    float e2 = exp2f(y2 - m), e3 = exp2f(y3 - m);
    float s = e0 + e1 + e2 + e3;
    #pragma unroll
    for (int w = 4; w >= 1; w >>= 1)
        s += __shfl_xor(s, w, 8);

    float rs = 1.0f / s;
    float ls = log2f(s);
    float p0 = e0 * rs, p1 = e1 * rs, p2 = e2 * rs, p3 = e3 * rs;
    float l0 = (y0 - m) - ls, l1 = (y1 - m) - ls;
    float l2 = (y2 - m) - ls, l3 = (y3 - m) - ls;

    half4v pv;
    pv[0] = (_Float16)fmaxf(p0, 1e-7f);
    pv[1] = (_Float16)fmaxf(p1, 1e-7f);
    pv[2] = (_Float16)fmaxf(p2, 1e-7f);
    pv[3] = (_Float16)fmaxf(p3, 1e-7f);
    *(half4v*)(P + (size_t)bl * (NK * NC) + t * 4) = pv;

    float hacc = p0 * l0 + p1 * l1 + p2 * l2 + p3 * l3;
    #pragma unroll
    for (int w = 32; w >= 1; w >>= 1)
        hacc += __shfl_xor(hacc, w);
    __shared__ float red[4];
    int lane = t & 63, wib = t >> 6;
    if (lane == 0) red[wib] = hacc;
    __syncthreads();
    if (t == 0) H2[bl] = red[0] + red[1] + red[2] + red[3];
}

// 576 blocks, 4 waves each. Block stages an 8x8 row-tile pair into LDS
// (P as f16, h as f16) and computes its pairs entirely from LDS.
__global__ void __launch_bounds__(256) pair_kernel(
        const _Float16* __restrict__ P,
        const float* __restrict__ H2,
        const float* __restrict__ hg,
        float* __restrict__ partials) {
    __shared__ _Float16 sPi[8][1024];   // 16 KB
    __shared__ _Float16 sPj[8][1024];   // 16 KB
    __shared__ _Float16 sHi[8][512];    //  8 KB
    __shared__ _Float16 sHj[8][512];    //  8 KB
    __shared__ float red[4][4];

    int tid  = threadIdx.x;
    int lane = tid & 63;
    int wib  = tid >> 6;

    int b   = blockIdx.x / TILES_PER_B;
    int t36 = blockIdx.x % TILES_PER_B;
    int ti = 0, rem = t36;
    while (rem >= 8 - ti) { rem -= 8 - ti; ++ti; }
    int tj = ti + rem;
    bool diag = (ti == tj);

    // ---- stage i-rows ----
    {
        const float4* srcP = (const float4*)(P + (size_t)(b * NL + ti * 8) * (NK * NC));
        float4* dP = (float4*)&sPi[0][0];
        #pragma unroll
        for (int k = 0; k < 4; ++k) dP[tid + 256 * k] = srcP[tid + 256 * k];

        const float4* srcH = (const float4*)(hg + (size_t)(b * NL + ti * 8) * ND);
        half4v* dH = (half4v*)&sHi[0][0];
        #pragma unroll
        for (int k = 0; k < 4; ++k) {
            float4 v = srcH[tid + 256 * k];
            half4v o;
            o[0] = (_Float16)v.x; o[1] = (_Float16)v.y;
            o[2] = (_Float16)v.z; o[3] = (_Float16)v.w;
            dH[tid + 256 * k] = o;
        }
    }
    // ---- stage j-rows (off-diagonal only) ----
    if (!diag) {
        const float4* srcP = (const float4*)(P + (size_t)(b * NL + tj * 8) * (NK * NC));
        float4* dP = (float4*)&sPj[0][0];
        #pragma unroll
        for (int k = 0; k < 4; ++k) dP[tid + 256 * k] = srcP[tid + 256 * k];

        const float4* srcH = (const float4*)(hg + (size_t)(b * NL + tj * 8) * ND);
        half4v* dH = (half4v*)&sHj[0][0];
        #pragma unroll
        for (int k = 0; k < 4; ++k) {
            float4 v = srcH[tid + 256 * k];
            half4v o;
            o[0] = (_Float16)v.x; o[1] = (_Float16)v.y;
            o[2] = (_Float16)v.z; o[3] = (_Float16)v.w;
            dH[tid + 256 * k] = o;
        }
    }
    __syncthreads();

    const float* H2i = H2 + b * NL + ti * 8;
    const float* H2j = H2 + b * NL + tj * 8;

    float attN = 0.0f, attC = 0.0f, repN = 0.0f, repC = 0.0f;

    int pbeg = diag ? wib * 7 : wib * 16;
    int pend = diag ? pbeg + 7 : pbeg + 16;

    for (int p = pbeg; p < pend; ++p) {
        int r, s;
        if (diag) {
            int q = p; r = 0;
            while (q >= 7 - r) { q -= 7 - r; ++r; }
            s = r + 1 + q;
        } else {
            r = p >> 3; s = p & 7;
        }

        const half8v* ar = (const half8v*)(&sPi[r][0] + lane * 16);
        const half8v* as = diag ? (const half8v*)(&sPi[s][0] + lane * 16)
                                : (const half8v*)(&sPj[s][0] + lane * 16);
        half8v a0 = ar[0], a1 = ar[1];
        half8v b0 = as[0], b1 = as[1];

        float S = 0.0f;
        #pragma unroll
        for (int q = 0; q < 8; ++q) {
            float t0 = (float)a0[q] + (float)b0[q];
            float t1 = (float)a1[q] + (float)b1[q];
            S = fmaf(t0, __log2f(t0), S);
            S = fmaf(t1, __log2f(t1), S);
        }

        half8v hr = *(const half8v*)(&sHi[r][0] + lane * 8);
        half8v hs = diag ? *(const half8v*)(&sHi[s][0] + lane * 8)
                         : *(const half8v*)(&sHj[s][0] + lane * 8);
        float macc = 0.0f;
        #pragma unroll
        for (int q = 0; q < 8; ++q) {
            float d = (float)hr[q] - (float)hs[q];
            macc = fmaf(d, d, macc);
        }

        #pragma unroll
        for (int w = 32; w >= 1; w >>= 1) {
            S    += __shfl_xor(S, w);
            macc += __shfl_xor(macc, w);
        }

        float stat = H2i[r] + H2j[s] + 64.0f - S;
        float mse  = macc * (1.0f / ND);
        if (stat < STAT_THRESHOLD) { attN += mse; attC += 1.0f; }
        else { repN += exp2f(-mse * L2E); repC += 1.0f; }
    }

    if (lane == 0) {
        red[wib][0] = attN; red[wib][1] = attC;
        red[wib][2] = repN; red[wib][3] = repC;
    }
    __syncthreads();
    if (tid < 4) {
        float v = red[0][tid] + red[1][tid] + red[2][tid] + red[3][tid];
        partials[blockIdx.x * 4 + tid] = v;
    }
}

__global__ void __launch_bounds__(256) finalize_kernel(
        const float* __restrict__ partials,
        float* __restrict__ out) {
    int tid = threadIdx.x;
    float a0 = 0.0f, a1 = 0.0f, a2 = 0.0f, a3 = 0.0f;
    for (int bkt = tid; bkt < PAIR_BLOCKS; bkt += 256) {
        a0 += partials[bkt * 4 + 0];
        a1 += partials[bkt * 4 + 1];
        a2 += partials[bkt * 4 + 2];
        a3 += partials[bkt * 4 + 3];
    }
    #pragma unroll
    for (int w = 32; w >= 1; w >>= 1) {
        a0 += __shfl_xor(a0, w);
        a1 += __shfl_xor(a1, w);
        a2 += __shfl_xor(a2, w);
        a3 += __shfl_xor(a3, w);
    }
    __shared__ float red[4][4];
    int lane = tid & 63, wib = tid >> 6;
    if (lane == 0) {
        red[wib][0] = a0; red[wib][1] = a1; red[wib][2] = a2; red[wib][3] = a3;
    }
    __syncthreads();
    if (tid == 0) {
        float s0 = red[0][0] + red[1][0] + red[2][0] + red[3][0];
        float s1 = red[0][1] + red[1][1] + red[2][1] + red[3][1];
        float s2 = red[0][2] + red[1][2] + red[2][2] + red[3][2];
        float s3 = red[0][3] + red[1][3] + red[2][3] + red[3][3];
        float la = s0 / (s1 + EPSF);
        float lr = s2 / (s3 + EPSF);
        out[0] = (la > 0.0f) ? la : 0.0f;
        out[1] = (lr > 0.0f) ? lr : 0.0f;
    }
}

extern "C" void kernel_launch(void* const* d_in, const int* in_sizes, int n_in,
                              void* d_out, int out_size, void* d_ws, size_t ws_size,
                              hipStream_t stream) {
    const float* prior = (const float*)d_in[0];
    const float* h     = (const float*)d_in[1];
    float* out = (float*)d_out;
    float* ws  = (float*)d_ws;

    float* partials = ws;                          // PAIR_BLOCKS*4 floats
    _Float16* P = (_Float16*)(ws + 4096);          // 1,048,576 halves
    float* H2 = ws + 4096 + (NB * NL * NK * NC / 2);  // after 2 MB of f16

    softmax_kernel<<<NB * NL, 256, 0, stream>>>(prior, P, H2);

    pair_kernel<<<PAIR_BLOCKS, 256, 0, stream>>>(P, H2, h, partials);

    finalize_kernel<<<1, 256, 0, stream>>>(partials, out);
}

// Round 5
// 30.551 us; speedup vs baseline: 27.5722x; 1.1149x over previous
//
#include <hip/hip_runtime.h>
#include <math.h>

#define NB 16
#define NL 64
#define NK 32
#define NC 32
#define ND 512
#define EPSF 1e-10f

#define TILES_PER_B 36
#define PAIR_BLOCKS (NB * TILES_PER_B)    // 576

// att iff jsd < 5  <=>  stat = sum_k [h2i_k + h2j_k + 2 - S_k] < 10/ln2
#define THRS 14.426950408889634f
#define L2E  1.4426950408889634f

typedef _Float16 half2v __attribute__((ext_vector_type(2)));
typedef _Float16 half4v __attribute__((ext_vector_type(4)));
typedef _Float16 half8v __attribute__((ext_vector_type(8)));

// ws layout (floats):
//   partials : PAIR_BLOCKS*4 at offset 0 (pad to 4096)
//   P  (f16) : 1,048,576 halves (2 MB)  at float offset 4096
//   H2 (f32x2): 1024 float2             after P
//   h16(f16) : 524,288 halves (1 MB)    after H2

// One block per (b,l). Writes P f16 (clamped), H2 split into (k<16, k>=16)
// halves, and converts this row of h to f16.
__global__ void __launch_bounds__(256) softmax_kernel(
        const float* __restrict__ prior,
        const float* __restrict__ hg,
        _Float16* __restrict__ P,
        float2* __restrict__ H2,
        _Float16* __restrict__ h16) {
    int bl = blockIdx.x;
    int t  = threadIdx.x;
    const float* src = prior + (size_t)bl * (NK * NC);

    float4 x = *(const float4*)(src + t * 4);
    float y0 = x.x * L2E, y1 = x.y * L2E, y2 = x.z * L2E, y3 = x.w * L2E;

    float m = fmaxf(fmaxf(y0, y1), fmaxf(y2, y3));
    #pragma unroll
    for (int w = 4; w >= 1; w >>= 1)
        m = fmaxf(m, __shfl_xor(m, w, 8));      // 8 lanes per k-row

    float e0 = exp2f(y0 - m), e1 = exp2f(y1 - m);
    float e2 = exp2f(y2 - m), e3 = exp2f(y3 - m);
    float s = e0 + e1 + e2 + e3;
    #pragma unroll
    for (int w = 4; w >= 1; w >>= 1)
        s += __shfl_xor(s, w, 8);

    float rs = 1.0f / s;
    float ls = __log2f(s);
    float p0 = e0 * rs, p1 = e1 * rs, p2 = e2 * rs, p3 = e3 * rs;
    float l0 = (y0 - m) - ls, l1 = (y1 - m) - ls;
    float l2 = (y2 - m) - ls, l3 = (y3 - m) - ls;

    half4v pv;
    pv[0] = (_Float16)fmaxf(p0, 1e-6f);
    pv[1] = (_Float16)fmaxf(p1, 1e-6f);
    pv[2] = (_Float16)fmaxf(p2, 1e-6f);
    pv[3] = (_Float16)fmaxf(p3, 1e-6f);
    *(half4v*)(P + (size_t)bl * (NK * NC) + t * 4) = pv;

    // h -> f16 for this row (512 floats, 2 per thread)
    float2 hv = *(const float2*)(hg + (size_t)bl * ND + t * 2);
    half2v hh; hh[0] = (_Float16)hv.x; hh[1] = (_Float16)hv.y;
    *(half2v*)(h16 + (size_t)bl * ND + t * 2) = hh;

    float hacc = p0 * l0 + p1 * l1 + p2 * l2 + p3 * l3;
    #pragma unroll
    for (int w = 32; w >= 1; w >>= 1)
        hacc += __shfl_xor(hacc, w);
    __shared__ float red[4];
    int lane = t & 63, wib = t >> 6;
    if (lane == 0) red[wib] = hacc;      // wave w covers k in [8w, 8w+8)
    __syncthreads();
    if (t == 0)
        H2[bl] = make_float2(red[0] + red[1], red[2] + red[3]);
}

// 576 blocks x 512 threads (8 waves). Block stages an 8x8 row-tile pair,
// wave w owns r-row w and loops s; phase-A (k<16) stat early-exits.
__global__ void __launch_bounds__(512) pair_kernel(
        const _Float16* __restrict__ P,
        const float2* __restrict__ H2,
        const _Float16* __restrict__ h16,
        float* __restrict__ partials) {
    __shared__ _Float16 sP[2][8][1024];   // 32 KB
    __shared__ _Float16 sH[2][8][512];    // 16 KB
    __shared__ float red[8][4];

    int tid  = threadIdx.x;
    int lane = tid & 63;
    int wv   = tid >> 6;

    int b   = blockIdx.x / TILES_PER_B;
    int t36 = blockIdx.x % TILES_PER_B;
    int ti = 0, rem = t36;
    while (rem >= 8 - ti) { rem -= 8 - ti; ++ti; }
    int tj = ti + rem;
    bool diag = (ti == tj);
    int bi0 = b * NL + ti * 8;
    int bj0 = b * NL + tj * 8;

    {   // stage i-group: 16 KB P + 8 KB h
        const float4* sp = (const float4*)(P + (size_t)bi0 * (NK * NC));
        float4* dp = (float4*)&sP[0][0][0];
        dp[tid] = sp[tid]; dp[tid + 512] = sp[tid + 512];
        const float4* sh = (const float4*)(h16 + (size_t)bi0 * ND);
        ((float4*)&sH[0][0][0])[tid] = sh[tid];
    }
    if (!diag) {
        const float4* sp = (const float4*)(P + (size_t)bj0 * (NK * NC));
        float4* dp = (float4*)&sP[1][0][0];
        dp[tid] = sp[tid]; dp[tid + 512] = sp[tid + 512];
        const float4* sh = (const float4*)(h16 + (size_t)bj0 * ND);
        ((float4*)&sH[1][0][0])[tid] = sh[tid];
    }
    __syncthreads();

    int gj = diag ? 0 : 1;
    int r  = wv;
    int sbeg = diag ? r + 1 : 0;

    // per-wave row-r state, loaded once
    half8v ar1 = *(const half8v*)&sP[0][r][lane * 8];        // k < 16
    half8v ar2 = *(const half8v*)&sP[0][r][512 + lane * 8];  // k >= 16
    half8v hr  = *(const half8v*)&sH[0][r][lane * 8];
    float2 h2i = H2[bi0 + r];

    float attN = 0.0f, attC = 0.0f, repN = 0.0f, repC = 0.0f;

    for (int s = sbeg; s < 8; ++s) {
        half8v bs1 = *(const half8v*)&sP[gj][s][lane * 8];
        half8v t1 = ar1 + bs1;                 // v_pk_add_f16 x4
        float S0 = 0.f, S1 = 0.f, S2 = 0.f, S3 = 0.f;
        {
            float f0 = (float)t1[0], f1 = (float)t1[1];
            float f2 = (float)t1[2], f3 = (float)t1[3];
            float f4 = (float)t1[4], f5 = (float)t1[5];
            float f6 = (float)t1[6], f7 = (float)t1[7];
            S0 = fmaf(f0, __log2f(f0), S0); S1 = fmaf(f1, __log2f(f1), S1);
            S2 = fmaf(f2, __log2f(f2), S2); S3 = fmaf(f3, __log2f(f3), S3);
            S0 = fmaf(f4, __log2f(f4), S0); S1 = fmaf(f5, __log2f(f5), S1);
            S2 = fmaf(f6, __log2f(f6), S2); S3 = fmaf(f7, __log2f(f7), S3);
        }
        float S16 = (S0 + S1) + (S2 + S3);

        half8v hs = *(const half8v*)&sH[gj][s][lane * 8];
        half8v d = hr - hs;                    // v_pk_add_f16(neg) x4
        float m0 = 0.f, m1 = 0.f;
        #pragma unroll
        for (int q = 0; q < 8; q += 2) {       // v_fma_mix-foldable
            m0 = fmaf((float)d[q],     (float)d[q],     m0);
            m1 = fmaf((float)d[q + 1], (float)d[q + 1], m1);
        }
        float mm = m0 + m1;

        #pragma unroll
        for (int w = 32; w >= 1; w >>= 1) {
            S16 += __shfl_xor(S16, w);
            mm  += __shfl_xor(mm, w);
        }

        float2 h2j = H2[bj0 + s];
        float statA = h2i.x + h2j.x + 32.0f - S16;
        float mse = mm * (1.0f / ND);

        bool isAtt = false;
        if (statA < THRS) {                    // undecided: do k>=16 phase
            half8v bs2 = *(const half8v*)&sP[gj][s][512 + lane * 8];
            half8v t2 = ar2 + bs2;
            float T0 = 0.f, T1 = 0.f, T2 = 0.f, T3 = 0.f;
            float g0 = (float)t2[0], g1 = (float)t2[1];
            float g2 = (float)t2[2], g3 = (float)t2[3];
            float g4 = (float)t2[4], g5 = (float)t2[5];
            float g6 = (float)t2[6], g7 = (float)t2[7];
            T0 = fmaf(g0, __log2f(g0), T0); T1 = fmaf(g1, __log2f(g1), T1);
            T2 = fmaf(g2, __log2f(g2), T2); T3 = fmaf(g3, __log2f(g3), T3);
            T0 = fmaf(g4, __log2f(g4), T0); T1 = fmaf(g5, __log2f(g5), T1);
            T2 = fmaf(g6, __log2f(g6), T2); T3 = fmaf(g7, __log2f(g7), T3);
            float SB = (T0 + T1) + (T2 + T3);
            #pragma unroll
            for (int w = 32; w >= 1; w >>= 1)
                SB += __shfl_xor(SB, w);
            float stat = statA + (h2i.y + h2j.y + 32.0f - SB);
            isAtt = (stat < THRS);
        }
        if (isAtt) { attN += mse; attC += 1.0f; }
        else       { repN += exp2f(-mse * L2E); repC += 1.0f; }
    }

    if (lane == 0) {
        red[wv][0] = attN; red[wv][1] = attC;
        red[wv][2] = repN; red[wv][3] = repC;
    }
    __syncthreads();
    if (tid < 4) {
        float v = 0.0f;
        #pragma unroll
        for (int w = 0; w < 8; ++w) v += red[w][tid];
        partials[blockIdx.x * 4 + tid] = v;
    }
}

__global__ void __launch_bounds__(256) finalize_kernel(
        const float* __restrict__ partials,
        float* __restrict__ out) {
    int tid = threadIdx.x;
    float a0 = 0.0f, a1 = 0.0f, a2 = 0.0f, a3 = 0.0f;
    for (int bkt = tid; bkt < PAIR_BLOCKS; bkt += 256) {
        a0 += partials[bkt * 4 + 0];
        a1 += partials[bkt * 4 + 1];
        a2 += partials[bkt * 4 + 2];
        a3 += partials[bkt * 4 + 3];
    }
    #pragma unroll
    for (int w = 32; w >= 1; w >>= 1) {
        a0 += __shfl_xor(a0, w);
        a1 += __shfl_xor(a1, w);
        a2 += __shfl_xor(a2, w);
        a3 += __shfl_xor(a3, w);
    }
    __shared__ float red[4][4];
    int lane = tid & 63, wib = tid >> 6;
    if (lane == 0) {
        red[wib][0] = a0; red[wib][1] = a1; red[wib][2] = a2; red[wib][3] = a3;
    }
    __syncthreads();
    if (tid == 0) {
        float s0 = red[0][0] + red[1][0] + red[2][0] + red[3][0];
        float s1 = red[0][1] + red[1][1] + red[2][1] + red[3][1];
        float s2 = red[0][2] + red[1][2] + red[2][2] + red[3][2];
        float s3 = red[0][3] + red[1][3] + red[2][3] + red[3][3];
        float la = s0 / (s1 + EPSF);
        float lr = s2 / (s3 + EPSF);
        out[0] = (la > 0.0f) ? la : 0.0f;
        out[1] = (lr > 0.0f) ? lr : 0.0f;
    }
}

extern "C" void kernel_launch(void* const* d_in, const int* in_sizes, int n_in,
                              void* d_out, int out_size, void* d_ws, size_t ws_size,
                              hipStream_t stream) {
    const float* prior = (const float*)d_in[0];
    const float* h     = (const float*)d_in[1];
    float* out = (float*)d_out;
    float* ws  = (float*)d_ws;

    float* partials = ws;                                   // 2304 floats
    _Float16* P = (_Float16*)(ws + 4096);                   // 1,048,576 halves
    float2* H2 = (float2*)(ws + 4096 + 524288);             // 1024 float2
    _Float16* h16 = (_Float16*)(ws + 4096 + 524288 + 2048); // 524,288 halves

    softmax_kernel<<<NB * NL, 256, 0, stream>>>(prior, h, P, H2, h16);

    pair_kernel<<<PAIR_BLOCKS, 512, 0, stream>>>(P, H2, h16, partials);

    finalize_kernel<<<1, 256, 0, stream>>>(partials, out);
}